// Round 10
// baseline (190.036 us; speedup 1.0000x reference)
//
#include <hip/hip_runtime.h>
#include <hip/hip_bf16.h>

// MetaConv2d fused hypernetwork + dynamic conv, bf16 MFMA. Round 10.
// out[bn,t,o] = sum_{c,k} x[bn,t+k,c] * w[bn,o,c,k] + bias[bn,o]
//   w[bn,p]   = meta[bn,:]·w_lin_w[p,:] + w_lin_b[p],  p = o*192 + c*3 + k
//
// KEY CHANGE vs r6 (best, 143us): waves/SIMD 4 -> 8 (TWO co-resident 16-wave
// blocks per CU). r8 showed halving waves/CU costs +43us (latency-chain bound);
// this doubles them instead: NT=4 nodes/block, wave=(node, t-quarter),
// acc[4]=16 f32, 64-reg waves via __launch_bounds__(1024,8), static LDS 64.5KB
// (<= 80KB/block for 2 blocks/CU). Accepted cost: hyper MFMA N-cols 4/16 used
// (2x hyper MFMA, util headroom) + 2x wlwbf L2 reads (L2-resident per XCD).
//
// Phase structure = r6's proven shape: 4 phases (2 c-halves x 2 o-halves),
//   hyper (12 tiles/wave in 4 groups of 3, fits 64-reg flight) -> barrier ->
//   conv (2x3 B + 3 A ds_reads, 6 MFMA) -> barrier.
// xsh: [4][64][XSTR=72] bf16 full-c (144B rows: odd granule stride -> 2-way).

#define BN_TOT   8192
#define C_IN     64
#define C_OUT    64
#define M_DIM    32
#define S_OUT    62

#define NT       4            // nodes per block
#define NTHREADS 1024         // 16 waves = 4 nodes x 4 t-quarters
#define XSTR     72           // shorts per x row (64 c + 8 pad), 144 B
#define XNODE    (64 * XSTR)  // 4608 shorts
#define OSTR     104          // shorts per o-row in w (96 j + 8 pad)
#define WNODE    (32 * OSTR + 8)   // 3336 shorts (one o-half: 32 o-rows)
#define WLW_ROWS 12288
#define WS_NEED  (WLW_ROWS * M_DIM * 2 + WLW_ROWS * 4)

typedef __attribute__((ext_vector_type(8))) short bf16x8;
typedef __attribute__((ext_vector_type(4))) float f32x4;

static __device__ __forceinline__ short f2bf(float f) {
    return __bfloat16_as_short(__float2bfloat16(f));
}

static __device__ __forceinline__ bf16x8 cvt8(float4 a, float4 b) {
    bf16x8 r;
    r[0] = f2bf(a.x); r[1] = f2bf(a.y); r[2] = f2bf(a.z); r[3] = f2bf(a.w);
    r[4] = f2bf(b.x); r[5] = f2bf(b.y); r[6] = f2bf(b.z); r[7] = f2bf(b.w);
    return r;
}

// ---------------- pre-pass 1: w_lin_w f32 -> bf16 ----------------
extern "C" __global__ void wlw_to_bf16(const float* __restrict__ src,
                                       short* __restrict__ dst) {
    const int i = (blockIdx.x * 256 + threadIdx.x) * 8;
    const float4 a = *reinterpret_cast<const float4*>(src + i);
    const float4 b = *reinterpret_cast<const float4*>(src + i + 4);
    *reinterpret_cast<bf16x8*>(dst + i) = cvt8(a, b);
}

// ---------------- pre-pass 2: wlb -> wlbR[o][k][c] f32 ----------------
extern "C" __global__ void wlb_rearr(const float* __restrict__ wlb,
                                     float* __restrict__ wlbR) {
    const int i = blockIdx.x * 256 + threadIdx.x;
    const int o = i / 192;
    const int r = i - o * 192;
    const int k = r >> 6;
    const int c = r & 63;
    wlbR[i] = wlb[o * 192 + c * 3 + k];
}

// ---------------- fused kernel ----------------
template <int USE_WS>
__global__ void __launch_bounds__(NTHREADS, 8)   // 8 waves/SIMD -> 2 blocks/CU
metaconv_fused(const float* __restrict__ meta,   // [8192][32]
               const float* __restrict__ x,      // [8192][64][64]
               const float* __restrict__ wlw,    // [12288][32] f32
               const short* __restrict__ wlwbf,  // [12288][32] bf16 (ws)
               const float* __restrict__ wlb,    // [12288]
               const float* __restrict__ wlbR,   // [64][3][64] (ws)
               const float* __restrict__ blw,    // [64][32]
               const float* __restrict__ blb,    // [64]
               float* __restrict__ out)          // [8192][62][64]
{
    __shared__ short xsh[NT * XNODE];     // 36.9 KB: x bf16, full 64 c
    __shared__ short wsh[NT * WNODE];     // 26.7 KB: one o-half of w
    __shared__ float bias_s[NT][C_OUT];   // 1 KB

    const int tid  = threadIdx.x;
    const int wave = tid >> 6;            // 0..15
    const int lane = tid & 63;
    const int l16  = lane & 15;
    const int g    = lane >> 4;
    const int node = wave & (NT - 1);     // 0..3
    const int tq   = wave >> 2;           // t-quarter 0..3
    const int bn0  = blockIdx.x * NT;

    // ---- stage x: full 64-c slab of this wave's (node, 16 rows) ----
    {
        const float* xsrc = x + (size_t)(bn0 + node) * (64 * C_IN);
        short* xd = xsh + node * XNODE;
        #pragma unroll
        for (int i = 0; i < 2; ++i) {
            const int gid = i * 64 + lane;       // 128 granules = 16 rows x 8
            const int row = tq * 16 + (gid >> 3);
            const int gr  = gid & 7;
            const float* p = xsrc + row * 64 + gr * 8;   // coalesced 64B/8 lanes
            const float4 a = *reinterpret_cast<const float4*>(p);
            const float4 b = *reinterpret_cast<const float4*>(p + 4);
            *reinterpret_cast<bf16x8*>(xd + row * XSTR + gr * 8) = cvt8(a, b);
        }
    }

    // per-block bias table (tid < 256): one (node,o) per thread
    if (tid < NT * C_OUT) {
        const int bnode = tid >> 6;
        const int o     = tid & 63;
        const float* mrow = meta + (size_t)(bn0 + bnode) * M_DIM;
        const float* brow = blw + o * M_DIM;
        float s = blb[o];
        #pragma unroll
        for (int m = 0; m < M_DIM; ++m) s += mrow[m] * brow[m];
        bias_s[bnode][o] = s;
    }

    // meta B-fragment: cols = node l16&3 (cols 4..15 duplicates, discarded)
    bf16x8 metaF;
    {
        const float* mp = meta + (size_t)(bn0 + (l16 & (NT - 1))) * M_DIM + g * 8;
        metaF = cvt8(*reinterpret_cast<const float4*>(mp),
                     *reinterpret_cast<const float4*>(mp + 4));
    }

    const f32x4 ZV = {0.f, 0.f, 0.f, 0.f};
    f32x4 acc[4];                         // [o-tile 0..3] — static idx only
    #pragma unroll
    for (int o = 0; o < 4; ++o) acc[o] = ZV;

    __syncthreads();                      // x staged, bias ready

    #pragma unroll
    for (int cc2 = 0; cc2 < 2; ++cc2) {
        const int c0 = cc2 * 32;
        #pragma unroll
        for (int ohf = 0; ohf < 2; ++ohf) {

            // ---- hyper: 12 tiles/wave = 4 groups of 3 (fits 64-reg flight) ----
            #pragma unroll 1
            for (int hc = 0; hc < 4; ++hc) {
                const int ou = hc >> 1;
                const int ch = hc & 1;
                const int o_l = wave * 2 + ou;        // 0..31 within half
                const int og  = ohf * 32 + o_l;       // global o
                #pragma unroll
                for (int k = 0; k < 3; ++k) {
                    const int pr = og * 192 + (c0 + ch * 16 + l16) * 3 + k;
                    bf16x8 aF;
                    f32x4 Cf;
                    if constexpr (USE_WS) {
                        aF = *reinterpret_cast<const bf16x8*>(wlwbf + (size_t)pr * M_DIM + g * 8);
                        const float4 cf = *reinterpret_cast<const float4*>(
                            wlbR + (og * 3 + k) * 64 + c0 + ch * 16 + g * 4);
                        Cf[0] = cf.x; Cf[1] = cf.y; Cf[2] = cf.z; Cf[3] = cf.w;
                    } else {
                        const float* wp = wlw + (size_t)pr * M_DIM + g * 8;
                        aF = cvt8(*reinterpret_cast<const float4*>(wp),
                                  *reinterpret_cast<const float4*>(wp + 4));
                        const int cb = c0 + ch * 16 + g * 4;
                        const int pb = og * 192 + k;
                        Cf[0] = wlb[pb + (cb + 0) * 3];
                        Cf[1] = wlb[pb + (cb + 1) * 3];
                        Cf[2] = wlb[pb + (cb + 2) * 3];
                        Cf[3] = wlb[pb + (cb + 3) * 3];
                    }
                    const f32x4 d = __builtin_amdgcn_mfma_f32_16x16x32_bf16(aF, metaF, Cf, 0, 0, 0);
                    if (l16 < NT) {
                        const int off = l16 * WNODE + o_l * OSTR + k * 32 + ch * 16 + g * 4;
                        *reinterpret_cast<short4*>(&wsh[off]) =
                            make_short4(f2bf(d[0]), f2bf(d[1]), f2bf(d[2]), f2bf(d[3]));
                    }
                }
            }
            __syncthreads();              // w ready for conv

            // ---- conv: 6 B + 3 A ds_reads, 6 MFMA into acc[ohf*2+ol] ----
            const short* wn = wsh + node * WNODE;
            const short* xn = xsh + node * XNODE;
            bf16x8 B[2][3];
            #pragma unroll
            for (int ol = 0; ol < 2; ++ol)
                #pragma unroll
                for (int k = 0; k < 3; ++k)
                    B[ol][k] = *reinterpret_cast<const bf16x8*>(
                        wn + (ol * 16 + l16) * OSTR + k * 32 + g * 8);
            bf16x8 A[3];
            #pragma unroll
            for (int k = 0; k < 3; ++k) {
                int row = tq * 16 + l16 + k;
                row = row < 63 ? row : 63;            // t>=62 rows discarded
                A[k] = *reinterpret_cast<const bf16x8*>(xn + row * XSTR + c0 + g * 8);
            }
            #pragma unroll
            for (int ol = 0; ol < 2; ++ol)
                #pragma unroll
                for (int k = 0; k < 3; ++k)
                    acc[ohf * 2 + ol] = __builtin_amdgcn_mfma_f32_16x16x32_bf16(
                        A[k], B[ol][k], acc[ohf * 2 + ol], 0, 0, 0);
            __syncthreads();              // conv done before next hyper overwrite
        }
    }

    // ---------------- epilogue: add bias, store f32 ----------------
    float* ob = out + (size_t)(bn0 + node) * (S_OUT * C_OUT);
    #pragma unroll
    for (int ot = 0; ot < 4; ++ot) {
        const int o  = ot * 16 + l16;
        const float bv = bias_s[node][o];
        #pragma unroll
        for (int r = 0; r < 4; ++r) {
            const int t = tq * 16 + g * 4 + r;
            if (t < S_OUT) ob[t * C_OUT + o] = acc[ot][r] + bv;
        }
    }
}

extern "C" void kernel_launch(void* const* d_in, const int* in_sizes, int n_in,
                              void* d_out, int out_size, void* d_ws, size_t ws_size,
                              hipStream_t stream) {
    const float* meta = (const float*)d_in[0];
    const float* x    = (const float*)d_in[1];
    const float* wlw  = (const float*)d_in[2];
    const float* wlb  = (const float*)d_in[3];
    const float* blw  = (const float*)d_in[4];
    const float* blb  = (const float*)d_in[5];
    float* out = (float*)d_out;
    (void)in_sizes; (void)n_in; (void)out_size;

    short* wlwbf = (short*)d_ws;
    float* wlbR  = (float*)((char*)d_ws + (size_t)WLW_ROWS * M_DIM * 2);

    if (ws_size >= (size_t)WS_NEED) {
        wlw_to_bf16<<<dim3(WLW_ROWS * M_DIM / (256 * 8)), dim3(256), 0, stream>>>(wlw, wlwbf);
        wlb_rearr<<<dim3(WLW_ROWS / 256), dim3(256), 0, stream>>>(wlb, wlbR);
        metaconv_fused<1><<<dim3(BN_TOT / NT), dim3(NTHREADS), 0, stream>>>(
            meta, x, wlw, wlwbf, wlb, wlbR, blw, blb, out);
    } else {
        metaconv_fused<0><<<dim3(BN_TOT / NT), dim3(NTHREADS), 0, stream>>>(
            meta, x, wlw, wlwbf, wlb, wlbR, blw, blb, out);
    }
}